// Round 1
// baseline (529.309 us; speedup 1.0000x reference)
//
#include <hip/hip_runtime.h>

#define NN 50000      // nodes
#define NE 800000     // edges
#define ND 128        // node_attr_dim
#define ED 16         // edge_attr_dim
#define HID 300       // hidden
#define KP1 192       // padded K for gemm1 (128+16 -> 192)
#define KP2 320       // padded K for gemm2 (300 -> 320)
#define NP 320        // padded N (300 -> 320)

#define SCAN_T 256
#define SCAN_B ((NN + SCAN_T - 1) / SCAN_T)   // 196 blocks

typedef __attribute__((ext_vector_type(8))) short short8;
typedef __attribute__((ext_vector_type(4))) float f32x4;

__device__ __forceinline__ unsigned short f2b(float f) {
    unsigned int u = __float_as_uint(f);
    u = (u + 0x7FFFu + ((u >> 16) & 1u)) >> 16;   // RNE
    return (unsigned short)u;
}
__device__ __forceinline__ float blo(unsigned int u) {
    return __uint_as_float(u << 16);
}
__device__ __forceinline__ float bhi(unsigned int u) {
    return __uint_as_float(u & 0xffff0000u);
}

// async global->LDS: 16B per lane, dest = wave-uniform base + lane*16
__device__ __forceinline__ void gload16(const void* g, void* l) {
    __builtin_amdgcn_global_load_lds(
        (const __attribute__((address_space(1))) void*)g,
        (__attribute__((address_space(3))) void*)l, 16, 0, 0);
}

// in-block inclusive scan of v across 256 threads (4 waves)
__device__ __forceinline__ int block_iscan(int v, int tid) {
    int lane = tid & 63;
    #pragma unroll
    for (int off = 1; off < 64; off <<= 1) {
        int t = __shfl_up(v, off);
        if (lane >= off) v += t;
    }
    __shared__ int wsum[4];
    int wid = tid >> 6;
    if (lane == 63) wsum[wid] = v;
    __syncthreads();
    int add = 0;
    #pragma unroll
    for (int w = 0; w < 4; ++w)
        if (w < wid) add += wsum[w];
    return v + add;
}

// ---------------------------------------------------------------- CSR build
__global__ void hist_kernel(const int* __restrict__ ei, int* __restrict__ rowptr) {
    int e = blockIdx.x * blockDim.x + threadIdx.x;
    if (e < NE) atomicAdd(&rowptr[ei[NE + e] + 1], 1);
}

// phase 1: local inclusive scan of rowptr[1..NN], block totals out
__global__ __launch_bounds__(SCAN_T) void scan1(int* __restrict__ rowptr,
                                                int* __restrict__ blockSums) {
    int i = blockIdx.x * SCAN_T + threadIdx.x;
    int v = (i < NN) ? rowptr[1 + i] : 0;
    v = block_iscan(v, threadIdx.x);
    if (i < NN) rowptr[1 + i] = v;
    if (threadIdx.x == SCAN_T - 1) blockSums[blockIdx.x] = v;
}

// phase 2: exclusive scan of block totals (196 <= 256, one block)
__global__ __launch_bounds__(SCAN_T) void scan2(int* __restrict__ blockSums) {
    int t = threadIdx.x;
    int orig = (t < SCAN_B) ? blockSums[t] : 0;
    int v = block_iscan(orig, t);
    if (t < SCAN_B) blockSums[t] = v - orig;   // exclusive
}

// phase 3: add block offsets; emit cursor[] (exclusive prefix per node)
__global__ __launch_bounds__(SCAN_T) void scan3(int* __restrict__ rowptr,
                                                const int* __restrict__ blockSums,
                                                int* __restrict__ cursor) {
    int i = blockIdx.x * SCAN_T + threadIdx.x;
    if (i < NN) {
        int v = rowptr[1 + i] + blockSums[blockIdx.x];
        rowptr[1 + i] = v;
        if (i + 1 < NN) cursor[i + 1] = v;
    }
    if (i == 0) cursor[0] = 0;
}

// packed CSR payloads: csr_sw = {src, w_bits}, csr_ew = {eid, w_bits}
__global__ void fill_kernel(const int* __restrict__ ei, const float* __restrict__ ew,
                            int* __restrict__ cursor, uint2* __restrict__ csr_sw,
                            uint2* __restrict__ csr_ew) {
    int e = blockIdx.x * blockDim.x + threadIdx.x;
    if (e < NE) {
        int d = ei[NE + e];
        int pos = atomicAdd(&cursor[d], 1);
        unsigned int wb = __float_as_uint(ew[e]);
        uint2 sw; sw.x = (unsigned int)ei[e]; sw.y = wb;
        uint2 ee; ee.x = (unsigned int)e;     ee.y = wb;
        csr_sw[pos] = sw;
        csr_ew[pos] = ee;
    }
}

// ------------------- cast x (fp32) -> A1 cols 0..127 (bf16), coalesced -----
__global__ __launch_bounds__(256) void cast_x(const float* __restrict__ x,
                                              unsigned short* __restrict__ A1) {
    int tid = blockIdx.x * blockDim.x + threadIdx.x;   // NN*32 threads
    if (tid >= NN * 32) return;
    int n = tid >> 5, q = tid & 31;
    float4 v = *(const float4*)&x[(size_t)n * ND + q * 4];
    unsigned short o[4] = {f2b(v.x), f2b(v.y), f2b(v.z), f2b(v.w)};
    *(uint2*)&A1[(size_t)n * KP1 + q * 4] = *(uint2*)o;
}

// ---- inc: wave per node; lanes = 4 edge-groups x 16 features; shfl reduce --
__global__ __launch_bounds__(256) void inc_kernel(
    const float* __restrict__ edge_attr,
    const int* __restrict__ rowptr,
    const uint2* __restrict__ csr_ew,
    unsigned short* __restrict__ A1) {
    int n = (blockIdx.x * blockDim.x + threadIdx.x) >> 6;
    int lane = threadIdx.x & 63;
    if (n >= NN) return;
    int g = lane >> 4, j = lane & 15;
    int lo = rowptr[n], hi = rowptr[n + 1];
    float v = 0.f;
    for (int k = lo + g; k < hi; k += 4) {
        uint2 ewp = csr_ew[k];
        float w = __uint_as_float(ewp.y);
        v += w * edge_attr[(size_t)ewp.x * ED + j];
    }
    v += __shfl_xor(v, 16);
    v += __shfl_xor(v, 32);
    if (lane < 16)
        A1[(size_t)n * KP1 + ND + lane] = f2b(v);
    else
        A1[(size_t)n * KP1 + ND + lane] = 0;   // pad cols 144..191
}

// B0T[n][k] = bf16(W0[k][n]) padded to [320][192]
__global__ void castB0(const float* __restrict__ W0, unsigned short* __restrict__ B0T) {
    int n = blockIdx.x, k = threadIdx.x;
    float v = (n < HID && k < ND + ED) ? W0[(size_t)k * HID + n] : 0.f;
    B0T[(size_t)n * KP1 + k] = f2b(v);
}

// BT[n][k] = bf16(W[k][n]) padded to [320][320]
__global__ void castB(const float* __restrict__ W, unsigned short* __restrict__ BT) {
    int n = blockIdx.x, k = threadIdx.x;
    float v = (n < HID && k < HID) ? W[(size_t)k * HID + n] : 0.f;
    BT[(size_t)n * KP2 + k] = f2b(v);
}

// ----------------------------------------------------------- MFMA bf16 GEMM
// 128x160 tile, 2x2 waves (each 64 rows x 80 cols), global_load_lds staging.
template <int MODE, int KP>
__global__ __launch_bounds__(256) void gemm_mfma(
    const unsigned short* __restrict__ A,   // [M, KP] bf16 row-major
    const unsigned short* __restrict__ BT,  // [320, KP] bf16 (B transposed)
    const float* __restrict__ bias,         // [300]
    const float* __restrict__ RES,          // MODE1: h0 [M,300] fp32
    float* __restrict__ C,                  // [M,300] fp32
    unsigned short* __restrict__ h0b,       // MODE0: [M,320] bf16
    int M)
{
    __shared__ unsigned short As[128][64];   // 16 KB
    __shared__ unsigned short Bs[160][64];   // 20 KB
    const int tid = threadIdx.x;
    const int m0 = blockIdx.x * 128;
    const int n0 = blockIdx.y * 160;
    const int wave = tid >> 6, lane = tid & 63;
    const int wm = wave >> 1, wn = wave & 1;
    const int quad = lane >> 4, lr = lane & 15;
    const int lr8 = lane >> 3;          // 0..7  (row within 8-row chunk)
    const int lc8 = (lane & 7) * 8;     // element col within 64-col tile
    f32x4 acc[4][5] = {};

    for (int kb = 0; kb < KP; kb += 64) {
        // A tile: 128 rows; wave stages rows [wave*32, wave*32+32)
        #pragma unroll
        for (int i = 0; i < 4; ++i) {
            int r = wave * 32 + i * 8;
            int mg = m0 + r + lr8; if (mg >= M) mg = M - 1;
            gload16(&A[(size_t)mg * KP + kb + lc8], &As[0][0] + r * 64);
        }
        // B tile: 160 rows; wave stages rows [wave*40, wave*40+40)
        #pragma unroll
        for (int i = 0; i < 5; ++i) {
            int r = wave * 40 + i * 8;
            gload16(&BT[(size_t)(n0 + r + lr8) * KP + kb + lc8], &Bs[0][0] + r * 64);
        }
        __syncthreads();   // drains vmcnt -> staging complete
        #pragma unroll
        for (int ks = 0; ks < 2; ++ks) {
            short8 a[4], b[5];
            #pragma unroll
            for (int tm = 0; tm < 4; ++tm)
                a[tm] = *(const short8*)&As[wm * 64 + tm * 16 + lr][ks * 32 + quad * 8];
            #pragma unroll
            for (int tn = 0; tn < 5; ++tn)
                b[tn] = *(const short8*)&Bs[wn * 80 + tn * 16 + lr][ks * 32 + quad * 8];
            #pragma unroll
            for (int tm = 0; tm < 4; ++tm)
                #pragma unroll
                for (int tn = 0; tn < 5; ++tn)
                    acc[tm][tn] = __builtin_amdgcn_mfma_f32_16x16x32_bf16(
                        a[tm], b[tn], acc[tm][tn], 0, 0, 0);
        }
        __syncthreads();
    }
    #pragma unroll
    for (int tm = 0; tm < 4; ++tm) {
        #pragma unroll
        for (int tn = 0; tn < 5; ++tn) {
            int ng = n0 + wn * 80 + tn * 16 + lr;
            #pragma unroll
            for (int r = 0; r < 4; ++r) {
                int mg = m0 + wm * 64 + tm * 16 + quad * 4 + r;
                if (mg < M && ng < HID) {
                    float v = acc[tm][tn][r] + bias[ng];
                    if (MODE == 1) v += RES[(size_t)mg * HID + ng];
                    v = fmaxf(v, 0.f);
                    C[(size_t)mg * HID + ng] = v;
                    if (MODE == 0) h0b[(size_t)mg * NP + ng] = f2b(v);
                }
            }
        }
    }
}

// ---------------- aggB[n] = bf16(mean_k w_k * h0b[src_k]) ------------------
__global__ __launch_bounds__(256) void agg_kernel(
    const unsigned short* __restrict__ h0b,   // [NN, 320] bf16
    const int* __restrict__ rowptr,
    const uint2* __restrict__ csr_sw,
    unsigned short* __restrict__ aggB)        // [NN, 320] bf16, pad cols = 0
{
    int n = (blockIdx.x * blockDim.x + threadIdx.x) >> 6;
    int lane = threadIdx.x & 63;
    if (n >= NN) return;
    int lo = rowptr[n], hi = rowptr[n + 1];
    float acc[8] = {};
    const uint4* h4 = (const uint4*)h0b;      // row stride = 40 uint4
    bool act = lane < 40;
    int k = lo;
    for (; k + 1 < hi; k += 2) {
        uint2 p0 = csr_sw[k], p1 = csr_sw[k + 1];
        int s0 = (int)p0.x, s1 = (int)p1.x;
        float w0 = __uint_as_float(p0.y), w1 = __uint_as_float(p1.y);
        uint4 r0 = {0, 0, 0, 0}, r1 = {0, 0, 0, 0};
        if (act) {
            r0 = h4[(size_t)s0 * 40 + lane];
            r1 = h4[(size_t)s1 * 40 + lane];
        }
        acc[0] += w0 * blo(r0.x); acc[1] += w0 * bhi(r0.x);
        acc[2] += w0 * blo(r0.y); acc[3] += w0 * bhi(r0.y);
        acc[4] += w0 * blo(r0.z); acc[5] += w0 * bhi(r0.z);
        acc[6] += w0 * blo(r0.w); acc[7] += w0 * bhi(r0.w);
        acc[0] += w1 * blo(r1.x); acc[1] += w1 * bhi(r1.x);
        acc[2] += w1 * blo(r1.y); acc[3] += w1 * bhi(r1.y);
        acc[4] += w1 * blo(r1.z); acc[5] += w1 * bhi(r1.z);
        acc[6] += w1 * blo(r1.w); acc[7] += w1 * bhi(r1.w);
    }
    if (k < hi) {
        uint2 p0 = csr_sw[k];
        int s0 = (int)p0.x;
        float w0 = __uint_as_float(p0.y);
        uint4 r0 = {0, 0, 0, 0};
        if (act) r0 = h4[(size_t)s0 * 40 + lane];
        acc[0] += w0 * blo(r0.x); acc[1] += w0 * bhi(r0.x);
        acc[2] += w0 * blo(r0.y); acc[3] += w0 * bhi(r0.y);
        acc[4] += w0 * blo(r0.z); acc[5] += w0 * bhi(r0.z);
        acc[6] += w0 * blo(r0.w); acc[7] += w0 * bhi(r0.w);
    }
    if (act) {
        float invd = 1.f / fmaxf((float)(hi - lo), 1.f);
        int cbase = lane * 8;
        unsigned int o[4];
        #pragma unroll
        for (int i = 0; i < 4; ++i) {
            int c0 = cbase + 2 * i, c1 = c0 + 1;
            unsigned int ulo = (c0 < HID) ? f2b(acc[2 * i] * invd) : 0;
            unsigned int uhi = (c1 < HID) ? f2b(acc[2 * i + 1] * invd) : 0;
            o[i] = ulo | (uhi << 16);
        }
        uint4* a4 = (uint4*)aggB;
        uint4 v; v.x = o[0]; v.y = o[1]; v.z = o[2]; v.w = o[3];
        a4[(size_t)n * 40 + lane] = v;
    }
}

// ---------------------------------------------------------------- launch
extern "C" void kernel_launch(void* const* d_in, const int* in_sizes, int n_in,
                              void* d_out, int out_size, void* d_ws, size_t ws_size,
                              hipStream_t stream) {
    const float* x           = (const float*)d_in[0];
    const float* edge_attr   = (const float*)d_in[1];
    const float* edge_weight = (const float*)d_in[2];
    const float* W0 = (const float*)d_in[4];
    const float* b0 = (const float*)d_in[5];
    const float* W  = (const float*)d_in[6];
    const float* b  = (const float*)d_in[7];
    const int* ei   = (const int*)d_in[8];

    float* out = (float*)d_out;
    float* h  = out;                          // output 0: [NN, HID]
    float* h0 = out + (size_t)NN * HID;       // output 1: [NN, HID]

    char* p = (char*)d_ws;
    auto alloc = [&](size_t bytes) { char* q = p; p += (bytes + 255) & ~(size_t)255; return q; };
    int*   rowptr  = (int*)  alloc((NN + 1) * sizeof(int));
    int*   cursor  = (int*)  alloc(NN * sizeof(int));
    int*   bsums   = (int*)  alloc(SCAN_B * sizeof(int));
    uint2* csr_sw  = (uint2*)alloc((size_t)NE * sizeof(uint2));
    uint2* csr_ew  = (uint2*)alloc((size_t)NE * sizeof(uint2));
    unsigned short* A1   = (unsigned short*)alloc((size_t)NN * KP1 * 2);
    unsigned short* h0b  = (unsigned short*)alloc((size_t)NN * NP * 2);
    unsigned short* aggB = (unsigned short*)alloc((size_t)NN * NP * 2);
    unsigned short* B0T  = (unsigned short*)alloc((size_t)NP * KP1 * 2);
    unsigned short* BT   = (unsigned short*)alloc((size_t)NP * KP2 * 2);

    hipMemsetAsync(rowptr, 0, (NN + 1) * sizeof(int), stream);
    hist_kernel<<<(NE + 255) / 256, 256, 0, stream>>>(ei, rowptr);
    scan1<<<SCAN_B, SCAN_T, 0, stream>>>(rowptr, bsums);
    scan2<<<1, SCAN_T, 0, stream>>>(bsums);
    scan3<<<SCAN_B, SCAN_T, 0, stream>>>(rowptr, bsums, cursor);
    fill_kernel<<<(NE + 255) / 256, 256, 0, stream>>>(ei, edge_weight, cursor,
                                                      csr_sw, csr_ew);
    castB0<<<NP, KP1, 0, stream>>>(W0, B0T);
    castB<<<NP, KP2, 0, stream>>>(W, BT);
    cast_x<<<(NN * 32 + 255) / 256, 256, 0, stream>>>(x, A1);
    inc_kernel<<<(NN + 3) / 4, 256, 0, stream>>>(edge_attr, rowptr, csr_ew, A1);

    dim3 g((NN + 127) / 128, NP / 160);
    gemm_mfma<0, KP1><<<g, 256, 0, stream>>>(A1, B0T, b0, nullptr, h0, h0b, NN);
    agg_kernel<<<(NN + 3) / 4, 256, 0, stream>>>(h0b, rowptr, csr_sw, aggB);
    gemm_mfma<1, KP2><<<g, 256, 0, stream>>>(aggB, BT, b, h0, h, nullptr, NN);
}

// Round 2
// 523.937 us; speedup vs baseline: 1.0103x; 1.0103x over previous
//
#include <hip/hip_runtime.h>

#define NN 50000      // nodes
#define NE 800000     // edges
#define ND 128        // node_attr_dim
#define ED 16         // edge_attr_dim
#define HID 300       // hidden
#define KP1 192       // padded K for gemm1 (128+16 -> 192)
#define KP2 320       // padded K for gemm2 (300 -> 320)
#define NP 320        // padded N (300 -> 320)

#define SCAN_T 256
#define SCAN_B ((NN + SCAN_T - 1) / SCAN_T)   // 196 blocks

typedef __attribute__((ext_vector_type(8))) short short8;
typedef __attribute__((ext_vector_type(4))) float f32x4;

__device__ __forceinline__ unsigned short f2b(float f) {
    unsigned int u = __float_as_uint(f);
    u = (u + 0x7FFFu + ((u >> 16) & 1u)) >> 16;   // RNE
    return (unsigned short)u;
}
__device__ __forceinline__ float blo(unsigned int u) {
    return __uint_as_float(u << 16);
}
__device__ __forceinline__ float bhi(unsigned int u) {
    return __uint_as_float(u & 0xffff0000u);
}

// async global->LDS: 16B per lane, dest = wave-uniform base + lane*16
__device__ __forceinline__ void gload16(const void* g, void* l) {
    __builtin_amdgcn_global_load_lds(
        (const __attribute__((address_space(1))) void*)g,
        (__attribute__((address_space(3))) void*)l, 16, 0, 0);
}

// in-block inclusive scan of v across 256 threads (4 waves)
__device__ __forceinline__ int block_iscan(int v, int tid) {
    int lane = tid & 63;
    #pragma unroll
    for (int off = 1; off < 64; off <<= 1) {
        int t = __shfl_up(v, off);
        if (lane >= off) v += t;
    }
    __shared__ int wsum[4];
    int wid = tid >> 6;
    if (lane == 63) wsum[wid] = v;
    __syncthreads();
    int add = 0;
    #pragma unroll
    for (int w = 0; w < 4; ++w)
        if (w < wid) add += wsum[w];
    return v + add;
}

// ---------------------------------------------------------------- CSR build
__global__ void hist_kernel(const int* __restrict__ ei, int* __restrict__ rowptr) {
    int e = blockIdx.x * blockDim.x + threadIdx.x;
    if (e < NE) atomicAdd(&rowptr[ei[NE + e] + 1], 1);
}

// phase 1: local inclusive scan of rowptr[1..NN], block totals out
__global__ __launch_bounds__(SCAN_T) void scan1(int* __restrict__ rowptr,
                                                int* __restrict__ blockSums) {
    int i = blockIdx.x * SCAN_T + threadIdx.x;
    int v = (i < NN) ? rowptr[1 + i] : 0;
    v = block_iscan(v, threadIdx.x);
    if (i < NN) rowptr[1 + i] = v;
    if (threadIdx.x == SCAN_T - 1) blockSums[blockIdx.x] = v;
}

// phase 2: exclusive scan of block totals (196 <= 256, one block)
__global__ __launch_bounds__(SCAN_T) void scan2(int* __restrict__ blockSums) {
    int t = threadIdx.x;
    int orig = (t < SCAN_B) ? blockSums[t] : 0;
    int v = block_iscan(orig, t);
    if (t < SCAN_B) blockSums[t] = v - orig;   // exclusive
}

// phase 3: add block offsets; emit cursor[] (exclusive prefix per node)
__global__ __launch_bounds__(SCAN_T) void scan3(int* __restrict__ rowptr,
                                                const int* __restrict__ blockSums,
                                                int* __restrict__ cursor) {
    int i = blockIdx.x * SCAN_T + threadIdx.x;
    if (i < NN) {
        int v = rowptr[1 + i] + blockSums[blockIdx.x];
        rowptr[1 + i] = v;
        if (i + 1 < NN) cursor[i + 1] = v;
    }
    if (i == 0) cursor[0] = 0;
}

// packed CSR payloads: csr_sw = {src, w_bits}, csr_ew = {eid, w_bits}
__global__ void fill_kernel(const int* __restrict__ ei, const float* __restrict__ ew,
                            int* __restrict__ cursor, uint2* __restrict__ csr_sw,
                            uint2* __restrict__ csr_ew) {
    int e = blockIdx.x * blockDim.x + threadIdx.x;
    if (e < NE) {
        int d = ei[NE + e];
        int pos = atomicAdd(&cursor[d], 1);
        unsigned int wb = __float_as_uint(ew[e]);
        uint2 sw; sw.x = (unsigned int)ei[e]; sw.y = wb;
        uint2 ee; ee.x = (unsigned int)e;     ee.y = wb;
        csr_sw[pos] = sw;
        csr_ew[pos] = ee;
    }
}

// ------------------- cast x (fp32) -> A1 cols 0..127 (bf16), coalesced -----
__global__ __launch_bounds__(256) void cast_x(const float* __restrict__ x,
                                              unsigned short* __restrict__ A1) {
    int tid = blockIdx.x * blockDim.x + threadIdx.x;   // NN*32 threads
    if (tid >= NN * 32) return;
    int n = tid >> 5, q = tid & 31;
    float4 v = *(const float4*)&x[(size_t)n * ND + q * 4];
    unsigned short o[4] = {f2b(v.x), f2b(v.y), f2b(v.z), f2b(v.w)};
    *(uint2*)&A1[(size_t)n * KP1 + q * 4] = *(uint2*)o;
}

// ---- inc: wave per node; lanes = 4 edge-groups x 16 features; shfl reduce --
__global__ __launch_bounds__(256) void inc_kernel(
    const float* __restrict__ edge_attr,
    const int* __restrict__ rowptr,
    const uint2* __restrict__ csr_ew,
    unsigned short* __restrict__ A1) {
    int n = (blockIdx.x * blockDim.x + threadIdx.x) >> 6;
    int lane = threadIdx.x & 63;
    if (n >= NN) return;
    int g = lane >> 4, j = lane & 15;
    int lo = rowptr[n], hi = rowptr[n + 1];
    float v = 0.f;
    for (int k = lo + g; k < hi; k += 4) {
        uint2 ewp = csr_ew[k];
        float w = __uint_as_float(ewp.y);
        v += w * edge_attr[(size_t)ewp.x * ED + j];
    }
    v += __shfl_xor(v, 16);
    v += __shfl_xor(v, 32);
    if (lane < 16)
        A1[(size_t)n * KP1 + ND + lane] = f2b(v);
    else
        A1[(size_t)n * KP1 + ND + lane] = 0;   // pad cols 144..191
}

// B0T[n][k] = bf16(W0[k][n]) padded to [320][192]
__global__ void castB0(const float* __restrict__ W0, unsigned short* __restrict__ B0T) {
    int n = blockIdx.x, k = threadIdx.x;
    float v = (n < HID && k < ND + ED) ? W0[(size_t)k * HID + n] : 0.f;
    B0T[(size_t)n * KP1 + k] = f2b(v);
}

// BT[n][k] = bf16(W[k][n]) padded to [320][320]
__global__ void castB(const float* __restrict__ W, unsigned short* __restrict__ BT) {
    int n = blockIdx.x, k = threadIdx.x;
    float v = (n < HID && k < HID) ? W[(size_t)k * HID + n] : 0.f;
    BT[(size_t)n * KP2 + k] = f2b(v);
}

// ----------------------------------------------------------- MFMA bf16 GEMM
// 128x160 tile, 2x2 waves, global_load_lds staging, double-buffered 2-phase
// pipeline, XOR-swizzled LDS (linear dest + inverse-swizzled source + swizzled
// ds_read addr; both sides use chunk ^= (row&7), rule #21).
template <int MODE, int KP>
__global__ __launch_bounds__(256) void gemm_mfma(
    const unsigned short* __restrict__ A,   // [M, KP] bf16 row-major
    const unsigned short* __restrict__ BT,  // [320, KP] bf16 (B transposed)
    const float* __restrict__ bias,         // [300]
    const float* __restrict__ RES,          // MODE1: h0 [M,300] fp32
    float* __restrict__ C,                  // [M,300] fp32
    unsigned short* __restrict__ h0b,       // MODE0: [M,320] bf16
    int M)
{
    __shared__ unsigned short As[2][128][64];   // 32 KB
    __shared__ unsigned short Bs[2][160][64];   // 40 KB
    const int tid = threadIdx.x;
    const int m0 = blockIdx.x * 128;
    const int n0 = blockIdx.y * 160;
    const int wave = tid >> 6, lane = tid & 63;
    const int wm = wave >> 1, wn = wave & 1;
    const int quad = lane >> 4, lr = lane & 15;
    const int lr8 = lane >> 3;                     // 0..7 row within 8-row group
    const int lc8 = ((lane & 7) ^ lr8) * 8;        // swizzled source col (elems)
    f32x4 acc[4][5] = {};

    auto stage = [&](int buf, int kb) {
        #pragma unroll
        for (int i = 0; i < 4; ++i) {              // A rows [wave*32, +32)
            int r = wave * 32 + i * 8;
            int mg = m0 + r + lr8; if (mg >= M) mg = M - 1;
            gload16(&A[(size_t)mg * KP + kb + lc8], &As[buf][0][0] + r * 64);
        }
        #pragma unroll
        for (int i = 0; i < 5; ++i) {              // B rows [wave*40, +40)
            int r = wave * 40 + i * 8;
            gload16(&BT[(size_t)(n0 + r + lr8) * KP + kb + lc8],
                    &Bs[buf][0][0] + r * 64);
        }
    };

    auto compute = [&](int buf) {
        #pragma unroll
        for (int ks = 0; ks < 2; ++ks) {
            // swizzled read chunk: (ks*4+quad) ^ (row&7); row&7 == lr&7 for
            // every fragment row (all row bases are multiples of 8)
            const int ch = ((ks * 4 + quad) ^ (lr & 7)) * 8;
            short8 a[4], b[5];
            #pragma unroll
            for (int tm = 0; tm < 4; ++tm)
                a[tm] = *(const short8*)&As[buf][wm * 64 + tm * 16 + lr][ch];
            #pragma unroll
            for (int tn = 0; tn < 5; ++tn)
                b[tn] = *(const short8*)&Bs[buf][wn * 80 + tn * 16 + lr][ch];
            #pragma unroll
            for (int tm = 0; tm < 4; ++tm)
                #pragma unroll
                for (int tn = 0; tn < 5; ++tn)
                    acc[tm][tn] = __builtin_amdgcn_mfma_f32_16x16x32_bf16(
                        a[tm], b[tn], acc[tm][tn], 0, 0, 0);
        }
    };

    // 2-phase pipeline: stage(next) issued BEFORE compute(cur); one barrier
    // (vmcnt drain) per K-step.
    const int NT = KP / 64;
    stage(0, 0);
    __syncthreads();
    int cur = 0;
    #pragma unroll 1
    for (int t = 0; t < NT - 1; ++t) {
        stage(cur ^ 1, (t + 1) * 64);
        compute(cur);
        __syncthreads();
        cur ^= 1;
    }
    compute(cur);

    #pragma unroll
    for (int tm = 0; tm < 4; ++tm) {
        #pragma unroll
        for (int tn = 0; tn < 5; ++tn) {
            int ng = n0 + wn * 80 + tn * 16 + lr;
            #pragma unroll
            for (int r = 0; r < 4; ++r) {
                int mg = m0 + wm * 64 + tm * 16 + quad * 4 + r;
                if (mg < M && ng < HID) {
                    float v = acc[tm][tn][r] + bias[ng];
                    if (MODE == 1) v += RES[(size_t)mg * HID + ng];
                    v = fmaxf(v, 0.f);
                    C[(size_t)mg * HID + ng] = v;
                    if (MODE == 0) h0b[(size_t)mg * NP + ng] = f2b(v);
                }
            }
        }
    }
}

// ---------------- aggB[n] = bf16(mean_k w_k * h0b[src_k]) ------------------
__global__ __launch_bounds__(256) void agg_kernel(
    const unsigned short* __restrict__ h0b,   // [NN, 320] bf16
    const int* __restrict__ rowptr,
    const uint2* __restrict__ csr_sw,
    unsigned short* __restrict__ aggB)        // [NN, 320] bf16, pad cols = 0
{
    int n = (blockIdx.x * blockDim.x + threadIdx.x) >> 6;
    int lane = threadIdx.x & 63;
    if (n >= NN) return;
    int lo = rowptr[n], hi = rowptr[n + 1];
    float acc[8] = {};
    const uint4* h4 = (const uint4*)h0b;      // row stride = 40 uint4
    bool act = lane < 40;
    int k = lo;
    for (; k + 1 < hi; k += 2) {
        uint2 p0 = csr_sw[k], p1 = csr_sw[k + 1];
        int s0 = (int)p0.x, s1 = (int)p1.x;
        float w0 = __uint_as_float(p0.y), w1 = __uint_as_float(p1.y);
        uint4 r0 = {0, 0, 0, 0}, r1 = {0, 0, 0, 0};
        if (act) {
            r0 = h4[(size_t)s0 * 40 + lane];
            r1 = h4[(size_t)s1 * 40 + lane];
        }
        acc[0] += w0 * blo(r0.x); acc[1] += w0 * bhi(r0.x);
        acc[2] += w0 * blo(r0.y); acc[3] += w0 * bhi(r0.y);
        acc[4] += w0 * blo(r0.z); acc[5] += w0 * bhi(r0.z);
        acc[6] += w0 * blo(r0.w); acc[7] += w0 * bhi(r0.w);
        acc[0] += w1 * blo(r1.x); acc[1] += w1 * bhi(r1.x);
        acc[2] += w1 * blo(r1.y); acc[3] += w1 * bhi(r1.y);
        acc[4] += w1 * blo(r1.z); acc[5] += w1 * bhi(r1.z);
        acc[6] += w1 * blo(r1.w); acc[7] += w1 * bhi(r1.w);
    }
    if (k < hi) {
        uint2 p0 = csr_sw[k];
        int s0 = (int)p0.x;
        float w0 = __uint_as_float(p0.y);
        uint4 r0 = {0, 0, 0, 0};
        if (act) r0 = h4[(size_t)s0 * 40 + lane];
        acc[0] += w0 * blo(r0.x); acc[1] += w0 * bhi(r0.x);
        acc[2] += w0 * blo(r0.y); acc[3] += w0 * bhi(r0.y);
        acc[4] += w0 * blo(r0.z); acc[5] += w0 * bhi(r0.z);
        acc[6] += w0 * blo(r0.w); acc[7] += w0 * bhi(r0.w);
    }
    if (act) {
        float invd = 1.f / fmaxf((float)(hi - lo), 1.f);
        int cbase = lane * 8;
        unsigned int o[4];
        #pragma unroll
        for (int i = 0; i < 4; ++i) {
            int c0 = cbase + 2 * i, c1 = c0 + 1;
            unsigned int ulo = (c0 < HID) ? f2b(acc[2 * i] * invd) : 0;
            unsigned int uhi = (c1 < HID) ? f2b(acc[2 * i + 1] * invd) : 0;
            o[i] = ulo | (uhi << 16);
        }
        uint4* a4 = (uint4*)aggB;
        uint4 v; v.x = o[0]; v.y = o[1]; v.z = o[2]; v.w = o[3];
        a4[(size_t)n * 40 + lane] = v;
    }
}

// ---------------------------------------------------------------- launch
extern "C" void kernel_launch(void* const* d_in, const int* in_sizes, int n_in,
                              void* d_out, int out_size, void* d_ws, size_t ws_size,
                              hipStream_t stream) {
    const float* x           = (const float*)d_in[0];
    const float* edge_attr   = (const float*)d_in[1];
    const float* edge_weight = (const float*)d_in[2];
    const float* W0 = (const float*)d_in[4];
    const float* b0 = (const float*)d_in[5];
    const float* W  = (const float*)d_in[6];
    const float* b  = (const float*)d_in[7];
    const int* ei   = (const int*)d_in[8];

    float* out = (float*)d_out;
    float* h  = out;                          // output 0: [NN, HID]
    float* h0 = out + (size_t)NN * HID;       // output 1: [NN, HID]

    char* p = (char*)d_ws;
    auto alloc = [&](size_t bytes) { char* q = p; p += (bytes + 255) & ~(size_t)255; return q; };
    int*   rowptr  = (int*)  alloc((NN + 1) * sizeof(int));
    int*   cursor  = (int*)  alloc(NN * sizeof(int));
    int*   bsums   = (int*)  alloc(SCAN_B * sizeof(int));
    uint2* csr_sw  = (uint2*)alloc((size_t)NE * sizeof(uint2));
    uint2* csr_ew  = (uint2*)alloc((size_t)NE * sizeof(uint2));
    unsigned short* A1   = (unsigned short*)alloc((size_t)NN * KP1 * 2);
    unsigned short* h0b  = (unsigned short*)alloc((size_t)NN * NP * 2);
    unsigned short* aggB = (unsigned short*)alloc((size_t)NN * NP * 2);
    unsigned short* B0T  = (unsigned short*)alloc((size_t)NP * KP1 * 2);
    unsigned short* BT   = (unsigned short*)alloc((size_t)NP * KP2 * 2);

    hipMemsetAsync(rowptr, 0, (NN + 1) * sizeof(int), stream);
    hist_kernel<<<(NE + 255) / 256, 256, 0, stream>>>(ei, rowptr);
    scan1<<<SCAN_B, SCAN_T, 0, stream>>>(rowptr, bsums);
    scan2<<<1, SCAN_T, 0, stream>>>(bsums);
    scan3<<<SCAN_B, SCAN_T, 0, stream>>>(rowptr, bsums, cursor);
    fill_kernel<<<(NE + 255) / 256, 256, 0, stream>>>(ei, edge_weight, cursor,
                                                      csr_sw, csr_ew);
    castB0<<<NP, KP1, 0, stream>>>(W0, B0T);
    castB<<<NP, KP2, 0, stream>>>(W, BT);
    cast_x<<<(NN * 32 + 255) / 256, 256, 0, stream>>>(x, A1);
    inc_kernel<<<(NN + 3) / 4, 256, 0, stream>>>(edge_attr, rowptr, csr_ew, A1);

    dim3 g((NN + 127) / 128, NP / 160);
    gemm_mfma<0, KP1><<<g, 256, 0, stream>>>(A1, B0T, b0, nullptr, h0, h0b, NN);
    agg_kernel<<<(NN + 3) / 4, 256, 0, stream>>>(h0b, rowptr, csr_sw, aggB);
    gemm_mfma<1, KP2><<<g, 256, 0, stream>>>(aggB, BT, b, h0, h, nullptr, NN);
}